// Round 8
// baseline (3420.449 us; speedup 1.0000x reference)
//
#include <hip/hip_runtime.h>

#define TT 1024
#define HH 128
#define NB 16
#define NBLK 16

typedef unsigned int u32;
typedef unsigned short u16;
typedef _Float16 f16;
typedef f16 f16x8 __attribute__((ext_vector_type(8)));
typedef float f32x4 __attribute__((ext_vector_type(4)));
typedef u32 u32x4 __attribute__((ext_vector_type(4)));

#define MFMA16(A, B, C) __builtin_amdgcn_mfma_f32_16x16x32_f16((A), (B), (C), 0, 0, 0)

__device__ __forceinline__ float ex2(float x) {
#if __has_builtin(__builtin_amdgcn_exp2f)
    return __builtin_amdgcn_exp2f(x);
#else
    extern "C" __device__ float __ocml_exp2_f32(float);
    return __ocml_exp2_f32(x);
#endif
}
__device__ __forceinline__ float rcpf_(float x) { return __builtin_amdgcn_rcpf(x); }
__device__ __forceinline__ void keepA(u32x4& v) { asm volatile("" : "+a"(v)); }

__device__ __forceinline__ float dpp_add(float v, const int ctrl) {
    int t;
    switch (ctrl) {
      case 0xB1:  t = __builtin_amdgcn_update_dpp(0, __float_as_int(v), 0xB1,  0xF, 0xF, true); break;
      case 0x4E:  t = __builtin_amdgcn_update_dpp(0, __float_as_int(v), 0x4E,  0xF, 0xF, true); break;
      case 0x141: t = __builtin_amdgcn_update_dpp(0, __float_as_int(v), 0x141, 0xF, 0xF, true); break;
      default:    t = __builtin_amdgcn_update_dpp(0, __float_as_int(v), 0x140, 0xF, 0xF, true); break;
    }
    return v + __int_as_float(t);
}
// full 16-lane-row sum (valid: uniformity grows stage by stage)
__device__ __forceinline__ float red16(float v) {
    v = dpp_add(v, 0xB1);   // xor1
    v = dpp_add(v, 0x4E);   // xor2
    v = dpp_add(v, 0x141);  // half-mirror == xor4 once quads uniform
    v = dpp_add(v, 0x140);  // mirror == xor8 once 8-blocks uniform
    return v;
}

// ---------------- prep: permute + activation-prescale + f16 hi/lo split ----
// Column permutation: p = w*128 + tile*16 + m, tile = us*4 + c
//   -> source gate row g = c*128 + (w*32 + us*16 + m).
// Gate scale baked in: i,f,o: -log2e ; g: +2*log2e  (activation = rcp(1+exp2(.)))
__global__ void prep(const float* __restrict__ Whh0, const float* __restrict__ Whh1,
                     const float* __restrict__ Wih1,
                     const float* __restrict__ bih0, const float* __restrict__ bhh0,
                     const float* __restrict__ bih1, const float* __restrict__ bhh1,
                     const float* __restrict__ Wih0,
                     f16* __restrict__ W0h, f16* __restrict__ W0l,
                     f16* __restrict__ W1h, f16* __restrict__ W1l,
                     f16* __restrict__ WFh,
                     float* __restrict__ b0p, float* __restrict__ b1p,
                     float* __restrict__ wx0p)
{
    const int i = blockIdx.x * 256 + threadIdx.x;   // 0..65535
    const int p = i >> 7, k = i & 127;
    const int w = p >> 7, tile = (p >> 4) & 7, m = p & 15;
    const int c = tile & 3, us = tile >> 2;
    const int j = w * 32 + us * 16 + m;
    const int g = c * 128 + j;
    const float sc = (c == 2) ? 2.8853900817779268f : -1.4426950408889634f;

    float w0 = Whh0[(size_t)g * HH + k] * sc;
    f16 h0 = (f16)w0; W0h[i] = h0; W0l[i] = (f16)(w0 - (float)h0);
    float w1 = Whh1[(size_t)g * HH + k] * sc;
    f16 h1 = (f16)w1; W1h[i] = h1; W1l[i] = (f16)(w1 - (float)h1);
    float wf = Wih1[(size_t)g * HH + k] * sc;
    WFh[i] = (f16)wf;
    if (k == 0) {
        b0p[p]  = (bih0[g] + bhh0[g]) * sc;
        b1p[p]  = (bih1[g] + bhh1[g]) * sc;
        wx0p[p] = Wih0[g] * sc;
    }
}

// ============================ layer 0 =======================================
// 16 blocks x 16 batch rows, 256 threads (4 waves, 1/SIMD, 512-reg budget).
// Per step: G[16,512] = H[16,128] @ W0^T via mfma 16x16x32 f16 (3-product split),
// + rank-1 x-term, fused epilogue; h kept in LDS u32(hi|lo), 1 barrier/step.
__global__ __launch_bounds__(256, 1) void lstm0(
    const float* __restrict__ x,
    const f16* __restrict__ W0h, const f16* __restrict__ W0l,
    const float* __restrict__ b0p, const float* __restrict__ wx0p,
    f16* __restrict__ h0g)
{
    const int tid = threadIdx.x;
    const int w = tid >> 6, l = tid & 63;
    const int m = l & 15, kg = l >> 4;
    const int b0 = blockIdx.x * NB;

    __shared__ __align__(16) float xT[TT][20];        // 80 KB (pad -> 16B align)
    __shared__ __align__(16) u32 hP[2][NB][HH + 12];  // [2][16][140] = 17.9 KB

    for (int idx = tid; idx < NB * TT; idx += 256) {
        const int row = idx >> 10, t = idx & (TT - 1);
        xT[t][row] = x[(size_t)(b0 + row) * TT + t];
    }
    for (int idx = tid; idx < 2 * NB * (HH + 12); idx += 256) ((u32*)hP)[idx] = 0;

    // B-frags: lane holds W[p = w*128+tile*16+m][ks*32+kg*8 .. +7]
    u32x4 Bh[8][4], Bl[8][4];
#pragma unroll
    for (int tile = 0; tile < 8; ++tile)
#pragma unroll
        for (int ks = 0; ks < 4; ++ks) {
            const int p = w * 128 + tile * 16 + m;
            const size_t off = (size_t)p * HH + ks * 32 + kg * 8;
            Bh[tile][ks] = *(const u32x4*)(W0h + off);
            Bl[tile][ks] = *(const u32x4*)(W0l + off);
        }
#pragma unroll
    for (int tile = 0; tile < 8; ++tile)
#pragma unroll
        for (int ks = 0; ks < 4; ++ks) keepA(Bl[tile][ks]);

    float bias8[8], wx8[8];
#pragma unroll
    for (int tile = 0; tile < 8; ++tile) {
        const int p = w * 128 + tile * 16 + m;
        bias8[tile] = b0p[p]; wx8[tile] = wx0p[p];
    }
    float cst[2][4] = {};
    f16* og = h0g + (size_t)blockIdx.x * TT * NB * HH;
    __syncthreads();

#pragma unroll 1
    for (int t = 0; t < TT; ++t) {
        const int cur = t & 1, nxt = cur ^ 1;
        f32x4 acc[8];
#pragma unroll
        for (int tile = 0; tile < 8; ++tile)
            acc[tile] = (f32x4){bias8[tile], bias8[tile], bias8[tile], bias8[tile]};

#pragma unroll
        for (int ks = 0; ks < 4; ++ks) {
            const u32* ap = &hP[cur][m][ks * 32 + kg * 8];
            const u32x4 q0 = *(const u32x4*)ap;
            const u32x4 q1 = *(const u32x4*)(ap + 4);
            u32x4 hi, lo;
            hi.x = __builtin_amdgcn_perm(q0.y, q0.x, 0x07060302u);
            hi.y = __builtin_amdgcn_perm(q0.w, q0.z, 0x07060302u);
            hi.z = __builtin_amdgcn_perm(q1.y, q1.x, 0x07060302u);
            hi.w = __builtin_amdgcn_perm(q1.w, q1.z, 0x07060302u);
            lo.x = __builtin_amdgcn_perm(q0.y, q0.x, 0x05040100u);
            lo.y = __builtin_amdgcn_perm(q0.w, q0.z, 0x05040100u);
            lo.z = __builtin_amdgcn_perm(q1.y, q1.x, 0x05040100u);
            lo.w = __builtin_amdgcn_perm(q1.w, q1.z, 0x05040100u);
            const f16x8 Ah = __builtin_bit_cast(f16x8, hi);
            const f16x8 Al = __builtin_bit_cast(f16x8, lo);
#pragma unroll
            for (int tile = 0; tile < 8; ++tile) {
                acc[tile] = MFMA16(Ah, __builtin_bit_cast(f16x8, Bh[tile][ks]), acc[tile]);
                acc[tile] = MFMA16(Al, __builtin_bit_cast(f16x8, Bh[tile][ks]), acc[tile]);
                acc[tile] = MFMA16(Ah, __builtin_bit_cast(f16x8, Bl[tile][ks]), acc[tile]);
            }
        }

        const float4 xr = *(const float4*)&xT[t][kg * 4];
        const float xre[4] = { xr.x, xr.y, xr.z, xr.w };
#pragma unroll
        for (int us = 0; us < 2; ++us) {
#pragma unroll
            for (int r = 0; r < 4; ++r) {
                const float xv = xre[r];
                const float pi = fmaf(xv, wx8[us * 4 + 0], acc[us * 4 + 0][r]);
                const float pf = fmaf(xv, wx8[us * 4 + 1], acc[us * 4 + 1][r]);
                const float pg = fmaf(xv, wx8[us * 4 + 2], acc[us * 4 + 2][r]);
                const float po = fmaf(xv, wx8[us * 4 + 3], acc[us * 4 + 3][r]);
                const float gi = rcpf_(1.f + ex2(pi));
                const float gf = rcpf_(1.f + ex2(pf));
                const float gg = fmaf(-2.f, rcpf_(1.f + ex2(pg)), 1.f);
                const float go = rcpf_(1.f + ex2(po));
                const float cc = fmaf(gf, cst[us][r], gi * gg);
                cst[us][r] = cc;
                const float th = fmaf(-2.f, rcpf_(1.f + ex2(2.8853900817779268f * cc)), 1.f);
                const float h = go * th;
                const f16 hh = (f16)h;
                const f16 hl = (f16)(h - (float)hh);
                const int row = kg * 4 + r, j = w * 32 + us * 16 + m;
                hP[nxt][row][j] = ((u32)__builtin_bit_cast(u16, hh) << 16) |
                                  (u32)__builtin_bit_cast(u16, hl);
                og[(size_t)(t * NB + row) * HH + j] = hh;
            }
        }
        __syncthreads();
    }
}

// ============================ layer 1 + FC ==================================
__global__ __launch_bounds__(256, 1) void lstm1(
    const f16* __restrict__ h0g,
    const f16* __restrict__ W1h, const f16* __restrict__ W1l,
    const f16* __restrict__ WFh, const float* __restrict__ b1p,
    const float* __restrict__ fcw, const float* __restrict__ fcb,
    float* __restrict__ out)
{
    const int tid = threadIdx.x;
    const int w = tid >> 6, l = tid & 63;
    const int m = l & 15, kg = l >> 4;
    const int b0 = blockIdx.x * NB;

    __shared__ __align__(16) u32 hP[2][NB][HH + 12];
    __shared__ __align__(16) float fcP[2][4][16];

    for (int idx = tid; idx < 2 * NB * (HH + 12); idx += 256) ((u32*)hP)[idx] = 0;

    u32x4 Bh[8][4], Bl[8][4], Bf[8][4];
#pragma unroll
    for (int tile = 0; tile < 8; ++tile)
#pragma unroll
        for (int ks = 0; ks < 4; ++ks) {
            const int p = w * 128 + tile * 16 + m;
            const size_t off = (size_t)p * HH + ks * 32 + kg * 8;
            Bh[tile][ks] = *(const u32x4*)(W1h + off);
            Bl[tile][ks] = *(const u32x4*)(W1l + off);
            Bf[tile][ks] = *(const u32x4*)(WFh + off);
        }
#pragma unroll
    for (int tile = 0; tile < 8; ++tile)
#pragma unroll
        for (int ks = 0; ks < 4; ++ks) { keepA(Bl[tile][ks]); keepA(Bf[tile][ks]); }

    float bias8[8];
#pragma unroll
    for (int tile = 0; tile < 8; ++tile) bias8[tile] = b1p[w * 128 + tile * 16 + m];
    const float fcw0 = fcw[w * 32 + m];
    const float fcw1 = fcw[w * 32 + 16 + m];
    const float fcbv = fcb[0];

    float cst[2][4] = {};
    const f16* hg = h0g + (size_t)blockIdx.x * TT * NB * HH;
    __syncthreads();

#pragma unroll 1
    for (int t = 0; t < TT; ++t) {
        const int cur = t & 1, nxt = cur ^ 1;

        if (w == 3 && t > 0 && l < 16) {   // deferred FC output for t-1
            const int pb = (t - 1) & 1;
            const float v = fcP[pb][0][l] + fcP[pb][1][l] + fcP[pb][2][l] + fcP[pb][3][l];
            out[(size_t)(b0 + l) * TT + (t - 1)] = v + fcbv;
        }

        // ff A-frags (h0_t from global/L1; issued early to hide latency)
        f16x8 A0[4];
#pragma unroll
        for (int ks = 0; ks < 4; ++ks)
            A0[ks] = *(const f16x8*)(hg + ((size_t)t * NB + m) * HH + ks * 32 + kg * 8);

        f32x4 acc[8];
#pragma unroll
        for (int tile = 0; tile < 8; ++tile)
            acc[tile] = (f32x4){bias8[tile], bias8[tile], bias8[tile], bias8[tile]};

        // recurrent term (3-product split)
#pragma unroll
        for (int ks = 0; ks < 4; ++ks) {
            const u32* ap = &hP[cur][m][ks * 32 + kg * 8];
            const u32x4 q0 = *(const u32x4*)ap;
            const u32x4 q1 = *(const u32x4*)(ap + 4);
            u32x4 hi, lo;
            hi.x = __builtin_amdgcn_perm(q0.y, q0.x, 0x07060302u);
            hi.y = __builtin_amdgcn_perm(q0.w, q0.z, 0x07060302u);
            hi.z = __builtin_amdgcn_perm(q1.y, q1.x, 0x07060302u);
            hi.w = __builtin_amdgcn_perm(q1.w, q1.z, 0x07060302u);
            lo.x = __builtin_amdgcn_perm(q0.y, q0.x, 0x05040100u);
            lo.y = __builtin_amdgcn_perm(q0.w, q0.z, 0x05040100u);
            lo.z = __builtin_amdgcn_perm(q1.y, q1.x, 0x05040100u);
            lo.w = __builtin_amdgcn_perm(q1.w, q1.z, 0x05040100u);
            const f16x8 Ah = __builtin_bit_cast(f16x8, hi);
            const f16x8 Al = __builtin_bit_cast(f16x8, lo);
#pragma unroll
            for (int tile = 0; tile < 8; ++tile) {
                acc[tile] = MFMA16(Ah, __builtin_bit_cast(f16x8, Bh[tile][ks]), acc[tile]);
                acc[tile] = MFMA16(Al, __builtin_bit_cast(f16x8, Bh[tile][ks]), acc[tile]);
                acc[tile] = MFMA16(Ah, __builtin_bit_cast(f16x8, Bl[tile][ks]), acc[tile]);
            }
        }
        // feedforward term (single product, W-hi x H0-hi)
#pragma unroll
        for (int ks = 0; ks < 4; ++ks)
#pragma unroll
            for (int tile = 0; tile < 8; ++tile)
                acc[tile] = MFMA16(A0[ks], __builtin_bit_cast(f16x8, Bf[tile][ks]), acc[tile]);

        // epilogue + h write + FC partial
        float pf4[4] = {0.f, 0.f, 0.f, 0.f};
#pragma unroll
        for (int us = 0; us < 2; ++us) {
            const float fw = us ? fcw1 : fcw0;
#pragma unroll
            for (int r = 0; r < 4; ++r) {
                const float pi = acc[us * 4 + 0][r];
                const float pfv = acc[us * 4 + 1][r];
                const float pg = acc[us * 4 + 2][r];
                const float po = acc[us * 4 + 3][r];
                const float gi = rcpf_(1.f + ex2(pi));
                const float gf = rcpf_(1.f + ex2(pfv));
                const float gg = fmaf(-2.f, rcpf_(1.f + ex2(pg)), 1.f);
                const float go = rcpf_(1.f + ex2(po));
                const float cc = fmaf(gf, cst[us][r], gi * gg);
                cst[us][r] = cc;
                const float th = fmaf(-2.f, rcpf_(1.f + ex2(2.8853900817779268f * cc)), 1.f);
                const float h = go * th;
                const f16 hh = (f16)h;
                const f16 hl = (f16)(h - (float)hh);
                const int row = kg * 4 + r, j = w * 32 + us * 16 + m;
                hP[nxt][row][j] = ((u32)__builtin_bit_cast(u16, hh) << 16) |
                                  (u32)__builtin_bit_cast(u16, hl);
                pf4[r] = fmaf(fw, h, pf4[r]);
            }
        }
#pragma unroll
        for (int r = 0; r < 4; ++r) pf4[r] = red16(pf4[r]);
        if (m == 0) {
            float4 v = { pf4[0], pf4[1], pf4[2], pf4[3] };
            *(float4*)&fcP[t & 1][w][kg * 4] = v;
        }
        __syncthreads();
    }
    if (w == 3 && l < 16) {
        const int pb = (TT - 1) & 1;
        const float v = fcP[pb][0][l] + fcP[pb][1][l] + fcP[pb][2][l] + fcP[pb][3][l];
        out[(size_t)(b0 + l) * TT + (TT - 1)] = v + fcbv;
    }
}

extern "C" void kernel_launch(void* const* d_in, const int* in_sizes, int n_in,
                              void* d_out, int out_size, void* d_ws, size_t ws_size,
                              hipStream_t stream)
{
    const float* x    = (const float*)d_in[0];
    const float* Wih0 = (const float*)d_in[1];
    const float* Whh0 = (const float*)d_in[2];
    const float* bih0 = (const float*)d_in[3];
    const float* bhh0 = (const float*)d_in[4];
    const float* Wih1 = (const float*)d_in[5];
    const float* Whh1 = (const float*)d_in[6];
    const float* bih1 = (const float*)d_in[7];
    const float* bhh1 = (const float*)d_in[8];
    const float* fcw  = (const float*)d_in[9];
    const float* fcb  = (const float*)d_in[10];
    float* out = (float*)d_out;

    f16* h0g = (f16*)d_ws;                               // 16*1024*16*128 f16 = 64 MiB
    f16* W0h = h0g + (size_t)NBLK * TT * NB * HH;
    f16* W0l = W0h + 512 * HH;
    f16* W1h = W0l + 512 * HH;
    f16* W1l = W1h + 512 * HH;
    f16* WFh = W1l + 512 * HH;
    float* b0p  = (float*)(WFh + 512 * HH);
    float* b1p  = b0p + 512;
    float* wx0p = b1p + 512;

    prep<<<256, 256, 0, stream>>>(Whh0, Whh1, Wih1, bih0, bhh0, bih1, bhh1, Wih0,
                                  W0h, W0l, W1h, W1l, WFh, b0p, b1p, wx0p);
    lstm0<<<NBLK, 256, 0, stream>>>(x, W0h, W0l, b0p, wx0p, h0g);
    lstm1<<<NBLK, 256, 0, stream>>>(h0g, W1h, W1l, WFh, b1p, fcw, fcb, out);
}

// Round 9
// 1446.816 us; speedup vs baseline: 2.3641x; 2.3641x over previous
//
#include <hip/hip_runtime.h>

#define TT 1024
#define HH 128

typedef unsigned int u32;
typedef unsigned short u16;
typedef _Float16 f16;
typedef f16 f16x2 __attribute__((ext_vector_type(2)));
typedef f16 f16x8 __attribute__((ext_vector_type(8)));
typedef float f32x4 __attribute__((ext_vector_type(4)));
typedef u32 u32x4 __attribute__((ext_vector_type(4)));

#define MFMA16(A, B, C) __builtin_amdgcn_mfma_f32_16x16x32_f16((A), (B), (C), 0, 0, 0)
#define K2L2E 2.8853900817779268f   /* 2*log2(e) */

__device__ __forceinline__ float ex2(float x) {
#if __has_builtin(__builtin_amdgcn_exp2f)
    return __builtin_amdgcn_exp2f(x);
#else
    extern "C" __device__ float __ocml_exp2_f32(float);
    return __ocml_exp2_f32(x);
#endif
}
__device__ __forceinline__ float rcp_(float x) { return __builtin_amdgcn_rcpf(x); }

__device__ __forceinline__ float fdot2_(u32 w, u32 h, float acc) {
#if __has_builtin(__builtin_amdgcn_fdot2)
    return __builtin_amdgcn_fdot2(__builtin_bit_cast(f16x2, w),
                                  __builtin_bit_cast(f16x2, h), acc, false);
#else
    const f16x2 a = __builtin_bit_cast(f16x2, w);
    const f16x2 b = __builtin_bit_cast(f16x2, h);
    return fmaf((float)a.y, (float)b.y, fmaf((float)a.x, (float)b.x, acc));
#endif
}

__device__ __forceinline__ float dpp_mov(float v, const int ctrl) {
    int t;
    switch (ctrl) {   // ICE ctrl; quad_perm broadcasts (R6/R7-verified)
      case 0x00: t = __builtin_amdgcn_update_dpp(0, __float_as_int(v), 0x00, 0xF, 0xF, true); break;
      case 0x55: t = __builtin_amdgcn_update_dpp(0, __float_as_int(v), 0x55, 0xF, 0xF, true); break;
      case 0xAA: t = __builtin_amdgcn_update_dpp(0, __float_as_int(v), 0xAA, 0xF, 0xF, true); break;
      default:   t = __builtin_amdgcn_update_dpp(0, __float_as_int(v), 0xFF, 0xF, 0xF, true); break;
    }
    return __int_as_float(t);
}
__device__ __forceinline__ float dpp_add(float v, const int ctrl) {
    int t;
    switch (ctrl) {
      case 0xB1:  t = __builtin_amdgcn_update_dpp(0, __float_as_int(v), 0xB1,  0xF, 0xF, true); break;
      case 0x4E:  t = __builtin_amdgcn_update_dpp(0, __float_as_int(v), 0x4E,  0xF, 0xF, true); break;
      default:    t = __builtin_amdgcn_update_dpp(0, __float_as_int(v), 0x141, 0xF, 0xF, true); break;
    }
    return v + __int_as_float(t);
}
__device__ __forceinline__ float red8(float v) {
    v = dpp_add(v, 0xB1); v = dpp_add(v, 0x4E); v = dpp_add(v, 0x141);
    return v;
}

// ---------------- prep -------------------------------------------------------
// Position p = 4*unit + gatetype (thread/lane order). Source gate row
// g = (p&3)*128 + (p>>2)  [R5-verified permutation]. Activation prescale baked:
// i,f,o: -log2e ; g: +2*log2e  (gate = A*rcp(1+exp2(a)) + C).
__global__ void prep(const float* __restrict__ Whh0, const float* __restrict__ Whh1,
                     const float* __restrict__ Wih1, const float* __restrict__ Wih0,
                     const float* __restrict__ bih0, const float* __restrict__ bhh0,
                     const float* __restrict__ bih1, const float* __restrict__ bhh1,
                     f16* __restrict__ Wpk0, f16* __restrict__ Wpk1,
                     f16* __restrict__ W1h,  f16* __restrict__ W1l,
                     float* __restrict__ bx0, float* __restrict__ wx0,
                     float* __restrict__ b1p)
{
    const int p = blockIdx.x;       // 0..511
    const int k = threadIdx.x;      // 0..127
    const int c = p & 3, u = p >> 2;
    const int g = c * 128 + u;
    const float sc = (c == 2) ? K2L2E : -1.4426950408889634f;

    Wpk0[p * HH + k] = (f16)(Whh0[(size_t)g * HH + k] * sc);
    Wpk1[p * HH + k] = (f16)(Whh1[(size_t)g * HH + k] * sc);
    const float wf = Wih1[(size_t)g * HH + k] * sc;
    const f16 wh = (f16)wf;
    W1h[p * HH + k] = wh;
    W1l[p * HH + k] = (f16)(wf - (float)wh);
    if (k == 0) {
        bx0[p] = (bih0[g] + bhh0[g]) * sc;
        wx0[p] = Wih0[g] * sc;
        b1p[p] = (bih1[g] + bhh1[g]) * sc;
    }
}

// ============================ layer 0 =======================================
// 256 blocks (1 batch row), 512 threads. Thread = gate position p=tid
// (unit u=tid>>2, gatetype tid&3), full K=128 via 64 v_dot2_f32_f16.
// Weights: 64 packed u32 VGPRs. Quad-DPP epilogue; h f16 in LDS; 1 barrier/step.
__global__ __launch_bounds__(512, 2) void lstm0(
    const float* __restrict__ x, const f16* __restrict__ Wpk0,
    const float* __restrict__ bx0, const float* __restrict__ wx0,
    f16* __restrict__ h0g)
{
    const int b = blockIdx.x;
    const int tid = threadIdx.x;
    const int u = tid >> 2;
    const bool lead = (tid & 3) == 0;
    const bool is_g = (tid & 3) == 2;
    const float Ag = is_g ? -2.f : 1.f;
    const float Cg = is_g ?  1.f : 0.f;

    __shared__ __align__(16) float xS[TT];          // 4 KB
    __shared__ __align__(16) u32 hS[2][64];         // h as packed f16 pairs
    __shared__ __align__(16) u16 hO[32][HH];        // 8 KB chunk staging for h0g

    xS[tid] = x[(size_t)b * TT + tid];
    xS[tid + 512] = x[(size_t)b * TT + tid + 512];
    if (tid < 128) hS[0][tid & 63] = 0u;            // zero both buffers

    u32x4 Wv[16];
    {
        const u32* wp = (const u32*)(Wpk0 + (size_t)tid * HH);
#pragma unroll
        for (int r = 0; r < 16; ++r) Wv[r] = *(const u32x4*)(wp + r * 4);
    }
    const float biasx = bx0[tid];
    const float wxv = wx0[tid];
    float c1 = 0.f;
    __syncthreads();

    f16* og = h0g + (size_t)b * TT * HH;

#pragma unroll 1
    for (int t0 = 0; t0 < TT; t0 += 32) {
#pragma unroll 1
        for (int i = 0; i < 32; ++i) {
            const int t = t0 + i;
            const u32* hcur = hS[t & 1];
            float a0 = 0.f, a1 = 0.f;
#pragma unroll
            for (int r = 0; r < 16; ++r) {
                const u32x4 hq = *(const u32x4*)(hcur + r * 4);
                a0 = fdot2_(Wv[r].x, hq.x, a0);
                a1 = fdot2_(Wv[r].y, hq.y, a1);
                a0 = fdot2_(Wv[r].z, hq.z, a0);
                a1 = fdot2_(Wv[r].w, hq.w, a1);
            }
            const float a = a0 + a1 + fmaf(xS[t], wxv, biasx);
            const float act = fmaf(Ag, rcp_(1.f + ex2(a)), Cg);
            const float gi = dpp_mov(act, 0x00);
            const float gf = dpp_mov(act, 0x55);
            const float gg = dpp_mov(act, 0xAA);
            const float go = dpp_mov(act, 0xFF);
            c1 = fmaf(gf, c1, gi * gg);
            const float h = go * fmaf(-2.f, rcp_(1.f + ex2(K2L2E * c1)), 1.f);
            if (lead) {
                const u16 hb = __builtin_bit_cast(u16, (f16)h);
                ((u16*)hS[(t + 1) & 1])[u] = hb;
                hO[i][u] = hb;
            }
            __syncthreads();
        }
        // dump 32-step h0 chunk, coalesced (8 KB)
        *(u32x4*)((u16*)og + (size_t)t0 * HH + tid * 8) = *(const u32x4*)(&hO[0][0] + tid * 8);
        __syncthreads();
    }
}

// ============================ layer 1 + FC ==================================
// Same rec core; per 32-step chunk an MFMA f16 2-product input-proj
// (A = prescaled W_ih1 hi/lo planes, B = h0 rows from global) fills
// xgS[32][512] f32 (bias folded into C-init), XOR-swizzled per row.
__global__ __launch_bounds__(512, 2) void lstm1(
    const f16* __restrict__ h0g, const f16* __restrict__ Wpk1,
    const f16* __restrict__ W1h, const f16* __restrict__ W1l,
    const float* __restrict__ b1p, const float* __restrict__ fcw,
    const float* __restrict__ fcb, float* __restrict__ out)
{
    const int b = blockIdx.x;
    const int tid = threadIdx.x;
    const int u = tid >> 2;
    const int wv = tid >> 6;
    const int lane = tid & 63;
    const int lr = lane & 15, lq = lane >> 4;
    const bool lead = (tid & 3) == 0;
    const bool is_g = (tid & 3) == 2;
    const float Ag = is_g ? -2.f : 1.f;
    const float Cg = is_g ?  1.f : 0.f;

    __shared__ __align__(16) float xgS[32 * 512];   // 64 KB
    __shared__ __align__(16) u32 hS[2][64];
    __shared__ __align__(16) float fcP[2][8];

    if (tid < 128) hS[0][tid & 63] = 0u;
    const float fcwv = fcw[u];
    const float fcbv = fcb[0];
    const int bp_addr = ((lane ^ 32) << 2);
    float c1 = 0.f;
    __syncthreads();

    const f16* hb0 = h0g + (size_t)b * TT * HH;
    float* ob = out + (size_t)b * TT;

#pragma unroll 1
    for (int t0 = 0; t0 < TT; t0 += 32) {
        // ---- proj: D = Wplanes * h0^T (2-product f16), bias in C-init ----
        {
            f16x8 B0[4], B1[4];
#pragma unroll
            for (int ks = 0; ks < 4; ++ks) {
                B0[ks] = *(const f16x8*)(hb0 + (size_t)(t0 + lr) * HH + ks * 32 + lq * 8);
                B1[ks] = *(const f16x8*)(hb0 + (size_t)(t0 + 16 + lr) * HH + ks * 32 + lq * 8);
            }
#pragma unroll
            for (int gtl = 0; gtl < 4; ++gtl) {
                const int g16 = (wv * 4 + gtl) * 16;
                const float4 bi = *(const float4*)&b1p[g16 + lq * 4];
                f32x4 a0 = {bi.x, bi.y, bi.z, bi.w};
                f32x4 a1 = a0;
#pragma unroll
                for (int ks = 0; ks < 4; ++ks) {
                    const f16x8 Ah = *(const f16x8*)(W1h + (size_t)(g16 + lr) * HH + ks * 32 + lq * 8);
                    const f16x8 Al = *(const f16x8*)(W1l + (size_t)(g16 + lr) * HH + ks * 32 + lq * 8);
                    a0 = MFMA16(Ah, B0[ks], a0);
                    a0 = MFMA16(Al, B0[ks], a0);
                    a1 = MFMA16(Ah, B1[ks], a1);
                    a1 = MFMA16(Al, B1[ks], a1);
                }
                // lane holds cols p = g16+lq*4+e, rows i = lr / 16+lr (R5-verified)
                const int gb = g16 + lq * 4;
                *(f32x4*)&xgS[lr * 512 + (gb ^ ((lr & 7) << 2))] = a0;
                *(f32x4*)&xgS[(16 + lr) * 512 + (gb ^ (((16 + lr) & 7) << 2))] = a1;
            }
        }
        __syncthreads();

        // reload rec weights each chunk (keeps proj-phase pressure low; L2-hot)
        u32x4 Wv[16];
        {
            const u32* wp = (const u32*)(Wpk1 + (size_t)tid * HH);
            asm volatile("" : "+v"(wp));
#pragma unroll
            for (int r = 0; r < 16; ++r) Wv[r] = *(const u32x4*)(wp + r * 4);
        }

        // ---- 32 recurrent steps, 1 barrier each ----
#pragma unroll 1
        for (int i = 0; i < 32; ++i) {
            const int t = t0 + i;
            if (wv == 7 && t > 0) {                 // deferred FC for t-1
                float v = (lane < 8) ? fcP[(t & 1) ^ 1][lane] : 0.f;
                v = red8(v);
                if (lane == 0) ob[t - 1] = v + fcbv;
            }
            const u32* hcur = hS[t & 1];
            float a0 = 0.f, a1 = 0.f;
#pragma unroll
            for (int r = 0; r < 16; ++r) {
                const u32x4 hq = *(const u32x4*)(hcur + r * 4);
                a0 = fdot2_(Wv[r].x, hq.x, a0);
                a1 = fdot2_(Wv[r].y, hq.y, a1);
                a0 = fdot2_(Wv[r].z, hq.z, a0);
                a1 = fdot2_(Wv[r].w, hq.w, a1);
            }
            const float a = a0 + a1 + xgS[i * 512 + (tid ^ ((i & 7) << 2))];
            const float act = fmaf(Ag, rcp_(1.f + ex2(a)), Cg);
            const float gi = dpp_mov(act, 0x00);
            const float gf = dpp_mov(act, 0x55);
            const float gg = dpp_mov(act, 0xAA);
            const float go = dpp_mov(act, 0xFF);
            c1 = fmaf(gf, c1, gi * gg);
            const float h = go * fmaf(-2.f, rcp_(1.f + ex2(K2L2E * c1)), 1.f);
            if (lead) ((u16*)hS[(t + 1) & 1])[u] = __builtin_bit_cast(u16, (f16)h);
            // FC partial: nonzero on lead lanes only; full-wave sum (R5-verified)
            float pf = lead ? h * fcwv : 0.f;
            pf = red8(pf);
            pf += __int_as_float(__builtin_amdgcn_ds_swizzle(__float_as_int(pf), 0x201F)); // xor8
            pf += __int_as_float(__builtin_amdgcn_ds_swizzle(__float_as_int(pf), 0x401F)); // xor16
            pf += __int_as_float(__builtin_amdgcn_ds_bpermute(bp_addr, __float_as_int(pf))); // xor32
            if (lane == 0) fcP[t & 1][wv] = pf;
            __syncthreads();
        }
    }
    if (wv == 7) {
        float v = (lane < 8) ? fcP[(TT - 1) & 1][lane] : 0.f;
        v = red8(v);
        if (lane == 0) ob[TT - 1] = v + fcbv;
    }
}

extern "C" void kernel_launch(void* const* d_in, const int* in_sizes, int n_in,
                              void* d_out, int out_size, void* d_ws, size_t ws_size,
                              hipStream_t stream)
{
    const float* x    = (const float*)d_in[0];
    const float* Wih0 = (const float*)d_in[1];
    const float* Whh0 = (const float*)d_in[2];
    const float* bih0 = (const float*)d_in[3];
    const float* bhh0 = (const float*)d_in[4];
    const float* Wih1 = (const float*)d_in[5];
    const float* Whh1 = (const float*)d_in[6];
    const float* bih1 = (const float*)d_in[7];
    const float* bhh1 = (const float*)d_in[8];
    const float* fcw  = (const float*)d_in[9];
    const float* fcb  = (const float*)d_in[10];
    float* out = (float*)d_out;

    f16* h0g  = (f16*)d_ws;                          // 256*1024*128 f16 = 64 MiB
    f16* Wpk0 = h0g + (size_t)256 * TT * HH;         // 128 KiB each
    f16* Wpk1 = Wpk0 + 512 * HH;
    f16* W1h  = Wpk1 + 512 * HH;
    f16* W1l  = W1h + 512 * HH;
    float* bx0 = (float*)(W1l + 512 * HH);
    float* wx0 = bx0 + 512;
    float* b1p = wx0 + 512;

    prep <<<512, 128, 0, stream>>>(Whh0, Whh1, Wih1, Wih0, bih0, bhh0, bih1, bhh1,
                                   Wpk0, Wpk1, W1h, W1l, bx0, wx0, b1p);
    lstm0<<<256, 512, 0, stream>>>(x, Wpk0, bx0, wx0, h0g);
    lstm1<<<256, 512, 0, stream>>>(h0g, Wpk1, W1h, W1l, b1p, fcw, fcb, out);
}